// Round 2
// baseline (706.316 us; speedup 1.0000x reference)
//
#include <hip/hip_runtime.h>

#define IMG   256
#define NPIX  65536          // 256*256
#define PH    63             // patches per side
#define NNODE 3969           // PH*PH
#define SN    4000           // padded node stride (mult of 32, 16B-aligned rows)
#define HID   64
#define GH    128
#define BATCH 4

typedef __attribute__((ext_vector_type(8))) short short8;
typedef __attribute__((ext_vector_type(4))) float float4v;
typedef unsigned short ushort_t;

__device__ inline ushort_t f2bf(float f) {
    union { float f; unsigned u; } v; v.f = f;
    unsigned r = v.u + 0x7FFF + ((v.u >> 16) & 1);   // RNE
    return (ushort_t)(r >> 16);
}

// ---------------------------------------------------------------------------
// adj fp32 [b][N][N] -> bf16 [b][N][SN], K-pad (3969..3999) zeroed
// ---------------------------------------------------------------------------
__global__ __launch_bounds__(256) void k_cvt_adj(const float* __restrict__ adj,
                                                 ushort_t* __restrict__ adjb) {
    int n = blockIdx.x, b = blockIdx.y;
    const float* src = adj + (size_t)(b * NNODE + n) * NNODE;
    unsigned* dst = (unsigned*)(adjb + (size_t)(b * NNODE + n) * SN);
    for (int c2 = threadIdx.x; c2 < SN / 2; c2 += 256) {
        int c = c2 * 2;
        float f0 = (c < NNODE) ? src[c] : 0.f;
        float f1 = (c + 1 < NNODE) ? src[c + 1] : 0.f;
        dst[c2] = (unsigned)f2bf(f0) | ((unsigned)f2bf(f1) << 16);
    }
}

// ---------------------------------------------------------------------------
// sup1T[b][g][n] = sum_pix patch[n][pix] * w3[pix][g]   (bf16 out, n-pad zeroed)
// ---------------------------------------------------------------------------
__global__ __launch_bounds__(256) void k_sup1(const float* __restrict__ in,
                                              const float* __restrict__ w3,
                                              ushort_t* __restrict__ sup1T) {
    int b = blockIdx.z;
    int g = blockIdx.y * 8 + (threadIdx.x >> 5);
    int n = blockIdx.x * 32 + (threadIdx.x & 31);
    ushort_t* dst = sup1T + (size_t)b * GH * SN + (size_t)g * SN + n;
    if (n >= NNODE) { *dst = 0; return; }
    int py = n / PH, px = n - py * PH;
    const float* base = in + (size_t)b * NPIX + (py * 4) * IMG + px * 4;
    float acc = 0.f;
#pragma unroll
    for (int i = 0; i < 8; ++i)
#pragma unroll
        for (int j = 0; j < 8; ++j)
            acc += base[i * IMG + j] * w3[(i * 8 + j) * GH + g];
    *dst = f2bf(acc);
}

// ---------------------------------------------------------------------------
// MFMA GEMM (transposed form): C[g][n] += sum_k supT[g][k] * adj[n][k]
// BK=64: two K=32 chunks staged+computed per barrier pair (halves barrier
// count vs BK=32). LDS rows 72 ushorts = 144 B (16B-aligned; same 2-way
// quarter-wave bank aliasing as the previous 80 B rows — free per m136).
// Tail: kiters = 31 (ks<3) or 32 (ks=3); last pair may have only chunk 0
// (wave-uniform has2). Max staged col: k0c+992 (ks<3) / 4000 exact (ks=3,
// reads zeroed K-pad, never overruns the SN row).
// ---------------------------------------------------------------------------
template <int G>
__global__ __launch_bounds__(256) void k_gemm_mfma(const ushort_t* __restrict__ adjb,
                                                   const ushort_t* __restrict__ supT,
                                                   float* __restrict__ C) {
    constexpr int FN = (G == 128) ? 4 : 2;
    const int b = blockIdx.z, ks = blockIdx.y;
    const int node0 = blockIdx.x * 128;
    const int t = threadIdx.x;
    const int lane = t & 63, w = t >> 6;
    const int l15 = lane & 15, q = lane >> 4;
    const int wm0 = (G == 128) ? (w & 1) * 64 : 0;
    const int wn0 = (G == 128) ? (w >> 1) * 64 : w * 32;

    __shared__ ushort_t Als[G][72];
    __shared__ ushort_t Bls[128][72];

    const int k0c = ks * 992;
    const int kend = (ks == 3) ? NNODE : k0c + 992;
    const int kiters = (kend - k0c + 31) >> 5;       // 31 (ks<3) or 32 (ks=3)
    const int npairs = (kiters + 1) >> 1;            // 16

    const ushort_t* Ab = supT + (size_t)b * G * SN;
    const ushort_t* Bb = adjb + (size_t)b * NNODE * SN;
    float* Cb = C + (size_t)b * G * SN;

    float4v acc[4][FN];
#pragma unroll
    for (int i = 0; i < 4; ++i)
#pragma unroll
        for (int j = 0; j < FN; ++j)
#pragma unroll
            for (int r = 0; r < 4; ++r) acc[i][j][r] = 0.f;

    for (int kp = 0; kp < npairs; ++kp) {
        const int kb0 = k0c + kp * 64;
        const bool has2 = (kp * 2 + 1 < kiters);     // wave-uniform
        // ---- stage chunk 0 (cols [kb0, kb0+32)) ----
#pragma unroll
        for (int i = 0; i < G / 64; ++i) {
            int idx = t + i * 256;
            int r = idx >> 2, s = idx & 3;
            *(uint4*)&Als[r][s * 8] =
                *(const uint4*)&Ab[(size_t)r * SN + kb0 + s * 8];
        }
#pragma unroll
        for (int i = 0; i < 2; ++i) {
            int idx = t + i * 256;
            int r = idx >> 2, s = idx & 3;
            *(uint4*)&Bls[r][s * 8] =
                *(const uint4*)&Bb[(size_t)(node0 + r) * SN + kb0 + s * 8];
        }
        // ---- stage chunk 1 (cols [kb0+32, kb0+64)) ----
        if (has2) {
#pragma unroll
            for (int i = 0; i < G / 64; ++i) {
                int idx = t + i * 256;
                int r = idx >> 2, s = idx & 3;
                *(uint4*)&Als[r][32 + s * 8] =
                    *(const uint4*)&Ab[(size_t)r * SN + kb0 + 32 + s * 8];
            }
#pragma unroll
            for (int i = 0; i < 2; ++i) {
                int idx = t + i * 256;
                int r = idx >> 2, s = idx & 3;
                *(uint4*)&Bls[r][32 + s * 8] =
                    *(const uint4*)&Bb[(size_t)(node0 + r) * SN + kb0 + 32 + s * 8];
            }
        }
        __syncthreads();
        // ---- compute chunk 0 ----
        {
            short8 af[4], bf[FN];
#pragma unroll
            for (int i = 0; i < 4; ++i)
                af[i] = *(const short8*)&Als[wm0 + i * 16 + l15][q * 8];
#pragma unroll
            for (int j = 0; j < FN; ++j)
                bf[j] = *(const short8*)&Bls[wn0 + j * 16 + l15][q * 8];
#pragma unroll
            for (int i = 0; i < 4; ++i)
#pragma unroll
                for (int j = 0; j < FN; ++j)
                    acc[i][j] = __builtin_amdgcn_mfma_f32_16x16x32_bf16(
                        af[i], bf[j], acc[i][j], 0, 0, 0);
        }
        // ---- compute chunk 1 ----
        if (has2) {
            short8 af[4], bf[FN];
#pragma unroll
            for (int i = 0; i < 4; ++i)
                af[i] = *(const short8*)&Als[wm0 + i * 16 + l15][32 + q * 8];
#pragma unroll
            for (int j = 0; j < FN; ++j)
                bf[j] = *(const short8*)&Bls[wn0 + j * 16 + l15][32 + q * 8];
#pragma unroll
            for (int i = 0; i < 4; ++i)
#pragma unroll
                for (int j = 0; j < FN; ++j)
                    acc[i][j] = __builtin_amdgcn_mfma_f32_16x16x32_bf16(
                        af[i], bf[j], acc[i][j], 0, 0, 0);
        }
        __syncthreads();
    }
#pragma unroll
    for (int i = 0; i < 4; ++i) {
        int gg = wm0 + i * 16 + q * 4;
#pragma unroll
        for (int j = 0; j < FN; ++j) {
            int nn = node0 + wn0 + j * 16 + l15;
            if (nn < NNODE) {
#pragma unroll
                for (int r = 0; r < 4; ++r)
                    unsafeAtomicAdd(&Cb[(size_t)(gg + r) * SN + nn], acc[i][j][r]);
            }
        }
    }
}

// ---------------------------------------------------------------------------
// sup2T[b][g][n] = sum_k relu(g1T[k][n] + gb3[k]) * w4[k][g]  (bf16, pad zeroed)
// ---------------------------------------------------------------------------
__global__ __launch_bounds__(256) void k_sup2(const float* __restrict__ g1T,
                                              const float* __restrict__ gb3,
                                              const float* __restrict__ w4,
                                              ushort_t* __restrict__ sup2T) {
    int b = blockIdx.z;
    int g = blockIdx.y * 8 + (threadIdx.x >> 5);
    int n = blockIdx.x * 32 + (threadIdx.x & 31);
    const float* gb = g1T + (size_t)b * GH * SN + n;
    float acc = 0.f;
#pragma unroll 8
    for (int k = 0; k < GH; ++k) {
        float v = fmaxf(gb[(size_t)k * SN] + gb3[k], 0.f);
        acc += v * w4[k * 64 + g];
    }
    sup2T[(size_t)b * 64 * SN + (size_t)g * SN + n] = (n < NNODE) ? f2bf(acc) : 0;
}

// ---------------------------------------------------------------------------
// conv1: 1 -> 64 ch, 3x3 SAME, relu. Output NHWC bf16: h1n[b][pix][64]
// ---------------------------------------------------------------------------
__global__ __launch_bounds__(256) void k_conv1(const float* __restrict__ in,
                                               const float* __restrict__ w,
                                               const float* __restrict__ bias,
                                               ushort_t* __restrict__ h1n) {
    int b = blockIdx.z;
    const float* inb = in + (size_t)b * NPIX;
    __shared__ float s[18][18];
    __shared__ float ws[576];
    int tx = threadIdx.x & 15, ty = threadIdx.x >> 4;
    int x0 = blockIdx.x * 16, y0 = blockIdx.y * 16;
    for (int idx = threadIdx.x; idx < 324; idx += 256) {
        int yy = idx / 18, xx = idx - yy * 18;
        int gy = y0 + yy - 1, gx = x0 + xx - 1;
        s[yy][xx] = (gy >= 0 && gy < IMG && gx >= 0 && gx < IMG) ? inb[gy * IMG + gx] : 0.f;
    }
    for (int idx = threadIdx.x; idx < 576; idx += 256) ws[idx] = w[idx];
    __syncthreads();
    float r[9];
#pragma unroll
    for (int dy = 0; dy < 3; ++dy)
#pragma unroll
        for (int dx = 0; dx < 3; ++dx) r[dy * 3 + dx] = s[ty + dy][tx + dx];
    int outp = (y0 + ty) * IMG + x0 + tx;
    ushort_t* dst = h1n + ((size_t)b * NPIX + outp) * 64;
#pragma unroll
    for (int sgrp = 0; sgrp < 8; ++sgrp) {
        unsigned pk[4];
#pragma unroll
        for (int h = 0; h < 4; ++h) {
            int oc0 = sgrp * 8 + h * 2;
            float a0 = bias[oc0], a1 = bias[oc0 + 1];
#pragma unroll
            for (int k = 0; k < 9; ++k) {
                a0 += r[k] * ws[oc0 * 9 + k];
                a1 += r[k] * ws[(oc0 + 1) * 9 + k];
            }
            a0 = fmaxf(a0, 0.f); a1 = fmaxf(a1, 0.f);
            pk[h] = (unsigned)f2bf(a0) | ((unsigned)f2bf(a1) << 16);
        }
        *(uint4*)&dst[sgrp * 8] = *(uint4*)pk;
    }
}

// ---------------------------------------------------------------------------
// prepack conv2 weights: cw2 [oc][ic][3][3] fp32 -> W2p [tap][oc][ic] bf16
// ---------------------------------------------------------------------------
__global__ __launch_bounds__(256) void k_prepack(const float* __restrict__ w,
                                                 ushort_t* __restrict__ W2p) {
    int idx = blockIdx.x * 256 + threadIdx.x;   // 9*64*64 = 36864
    if (idx >= 36864) return;
    int tap = idx >> 12, rem = idx & 4095;
    int oc = rem >> 6, ic = rem & 63;
    W2p[idx] = f2bf(w[(oc * 64 + ic) * 9 + tap]);
}

// ---------------------------------------------------------------------------
// conv2 implicit-GEMM MFMA: 64oc x (32x8 pixel tile), K = 9 taps x 64 ic.
// h1 NHWC bf16 in; h2 NCHW fp32 out (+bias+relu).
// LDS: full input halo 34x10 x 64ic, ic padded to 72 (2-way max bank alias,
// 144B rows keep 16B alignment). No barriers in the K loop.
// ---------------------------------------------------------------------------
__global__ __launch_bounds__(256) void k_conv2(const ushort_t* __restrict__ h1n,
                                               const ushort_t* __restrict__ W2p,
                                               const float* __restrict__ bias,
                                               float* __restrict__ h2) {
    __shared__ ushort_t Xs[340 * 72];           // 48,960 B
    const int b = blockIdx.z;
    const ushort_t* h1b = h1n + (size_t)b * NPIX * 64;
    float* h2b = h2 + (size_t)b * 64 * NPIX;
    const int t = threadIdx.x;
    const int lane = t & 63, w = t >> 6;
    const int l15 = lane & 15, q = lane >> 4;
    const int x0 = blockIdx.x * 32, y0 = blockIdx.y * 8;

    // stage halo: 340 pixels x 64 ic bf16 (8 x 16B chunks per pixel)
    for (int idx = t; idx < 2720; idx += 256) {
        int hp = idx >> 3, s = idx & 7;
        int hy = hp / 34, hx = hp - hy * 34;
        int gy = y0 + hy - 1, gx = x0 + hx - 1;
        uint4 v = {0u, 0u, 0u, 0u};
        if (gy >= 0 && gy < IMG && gx >= 0 && gx < IMG)
            v = *(const uint4*)&h1b[((size_t)gy * IMG + gx) * 64 + s * 8];
        *(uint4*)&Xs[hp * 72 + s * 8] = v;
    }
    __syncthreads();

    const int wn0 = w * 64;                     // wave's 64-pixel strip
    int pbase[4];
#pragma unroll
    for (int j = 0; j < 4; ++j) {
        int p = wn0 + j * 16 + l15;
        pbase[j] = (p >> 5) * 34 + (p & 31);
    }

    float4v acc[4][4];
#pragma unroll
    for (int i = 0; i < 4; ++i)
#pragma unroll
        for (int j = 0; j < 4; ++j)
#pragma unroll
            for (int r = 0; r < 4; ++r) acc[i][j][r] = 0.f;

    for (int tap = 0; tap < 9; ++tap) {
        int ky = tap / 3, kx = tap - ky * 3;
        const ushort_t* wp = W2p + tap * 4096;
#pragma unroll
        for (int c = 0; c < 2; ++c) {
            short8 af[4], bf[4];
#pragma unroll
            for (int i = 0; i < 4; ++i)
                af[i] = *(const short8*)&wp[(i * 16 + l15) * 64 + c * 32 + q * 8];
#pragma unroll
            for (int j = 0; j < 4; ++j)
                bf[j] = *(const short8*)&Xs[(pbase[j] + ky * 34 + kx) * 72 + c * 32 + q * 8];
#pragma unroll
            for (int i = 0; i < 4; ++i)
#pragma unroll
                for (int j = 0; j < 4; ++j)
                    acc[i][j] = __builtin_amdgcn_mfma_f32_16x16x32_bf16(
                        af[i], bf[j], acc[i][j], 0, 0, 0);
        }
    }

    // epilogue: D col = pixel (lane&15), row = oc (q*4+r)
#pragma unroll
    for (int i = 0; i < 4; ++i) {
#pragma unroll
        for (int j = 0; j < 4; ++j) {
            int p = wn0 + j * 16 + l15;
            int y = y0 + (p >> 5), x = x0 + (p & 31);
#pragma unroll
            for (int r = 0; r < 4; ++r) {
                int oc = i * 16 + q * 4 + r;
                h2b[(size_t)oc * NPIX + (size_t)y * IMG + x] =
                    fmaxf(acc[i][j][r] + bias[oc], 0.f);
            }
        }
    }
}

// ---------------------------------------------------------------------------
// combine: out = relu( tmp1 + conv3(h2) + gather(g2T + gb4)/cnt ), batched z=b
// ---------------------------------------------------------------------------
__global__ __launch_bounds__(256) void k_combine(const float* __restrict__ in,
                                                 const float* __restrict__ proj,
                                                 const float* __restrict__ lamp,
                                                 const float* __restrict__ h2,
                                                 const float* __restrict__ wc,
                                                 const float* __restrict__ bc,
                                                 const float* __restrict__ g2T,
                                                 const float* __restrict__ gb4,
                                                 float* __restrict__ out) {
    int b = blockIdx.z;
    const float* inb = in + (size_t)b * NPIX;
    const float* prb = proj + (size_t)b * NPIX;
    const float* h2b = h2 + (size_t)b * 64 * NPIX;
    const float* g2b = g2T + (size_t)b * 64 * SN;
    __shared__ float s[16][18][18];
    __shared__ float ws[144];
    int tx = threadIdx.x & 15, ty = threadIdx.x >> 4;
    int x0 = blockIdx.x * 16, y0 = blockIdx.y * 16;
    int y = y0 + ty, x = x0 + tx;

    float acc = bc[0];
    for (int icc = 0; icc < 4; ++icc) {
        for (int idx = threadIdx.x; idx < 16 * 324; idx += 256) {
            int ic = idx / 324, rem = idx - ic * 324;
            int yy = rem / 18, xx = rem - yy * 18;
            int gy = y0 + yy - 1, gx = x0 + xx - 1;
            s[ic][yy][xx] = (gy >= 0 && gy < IMG && gx >= 0 && gx < IMG)
                                ? h2b[(icc * 16 + ic) * NPIX + gy * IMG + gx]
                                : 0.f;
        }
        for (int idx = threadIdx.x; idx < 144; idx += 256) ws[idx] = wc[icc * 144 + idx];
        __syncthreads();
#pragma unroll 4
        for (int ic = 0; ic < 16; ++ic) {
#pragma unroll
            for (int ky = 0; ky < 3; ++ky)
#pragma unroll
                for (int kx = 0; kx < 3; ++kx)
                    acc += s[ic][ty + ky][tx + kx] * ws[ic * 9 + ky * 3 + kx];
        }
        __syncthreads();
    }

    float iv = inb[y * IMG + x], pv = prb[y * IMG + x];
    float tmp1 = iv + lamp[0] * (pv - iv);

    int pylo = (y >= 4) ? ((y - 4) >> 2) : 0;
    int pyhi = min(62, y >> 2);
    int pxlo = (x >= 4) ? ((x - 4) >> 2) : 0;
    int pxhi = min(62, x >> 2);
    float sum = 0.f;
    int cnt = 0;
    for (int py = pylo; py <= pyhi; ++py)
        for (int px = pxlo; px <= pxhi; ++px) {
            int pix = (y - 4 * py) * 8 + (x - 4 * px);
            sum += g2b[(size_t)pix * SN + (py * PH + px)] + gb4[pix];
            ++cnt;
        }
    float tmp3 = sum / (float)cnt;

    out[(size_t)b * NPIX + y * IMG + x] = fmaxf(tmp1 + acc + tmp3, 0.f);
}

// ---------------------------------------------------------------------------
extern "C" void kernel_launch(void* const* d_in, const int* in_sizes, int n_in,
                              void* d_out, int out_size, void* d_ws, size_t ws_size,
                              hipStream_t stream) {
    const float* input = (const float*)d_in[0];
    const float* proj  = (const float*)d_in[1];
    const float* adj   = (const float*)d_in[2];
    const float* lam   = (const float*)d_in[3];
    const float* cw1   = (const float*)d_in[4];
    const float* cb1   = (const float*)d_in[5];
    const float* cw2   = (const float*)d_in[6];
    const float* cb2   = (const float*)d_in[7];
    const float* cw3   = (const float*)d_in[8];
    const float* cb3   = (const float*)d_in[9];
    const float* gw3   = (const float*)d_in[10];
    const float* gb3   = (const float*)d_in[11];
    const float* gw4   = (const float*)d_in[12];
    const float* gb4   = (const float*)d_in[13];
    float* out = (float*)d_out;

    // ws layout (bytes), total 145,440,000 (same as round 2):
    //   g2T fp32 [4][64][SN]                    @ 0          (4,096,000)
    //   pool @ 4,096,000:
    //     GCN phase: adjb bf16 [4][N][SN]       (127,008,000)
    //                sup1T bf16 [4][128][SN]    (4,096,000)
    //                g1T  fp32 [4][128][SN]     (8,192,000)
    //                sup2T bf16 [4][64][SN]     (2,048,000)
    //     conv phase (reuses pool, stream-ordered after gemm<64>):
    //                h1n bf16 [4][NPIX][64]     (33,554,432)
    //                h2  fp32 [4][64][NPIX]     (67,108,864)
    //                W2p bf16 [9][64][64]       (73,728)
    char* base = (char*)d_ws;
    float*    g2T   = (float*)base;
    char*     pool  = base + 4096000;
    ushort_t* adjb  = (ushort_t*)pool;
    ushort_t* sup1T = (ushort_t*)(pool + 127008000);
    float*    g1T   = (float*)(pool + 127008000 + 4096000);
    ushort_t* sup2T = (ushort_t*)(pool + 127008000 + 4096000 + 8192000);
    ushort_t* h1n   = (ushort_t*)pool;
    float*    h2    = (float*)(pool + 33554432);
    ushort_t* W2p   = (ushort_t*)(pool + 33554432 + 67108864);

    dim3 blk(256);

    hipMemsetAsync(g1T, 0, 8192000, stream);
    hipMemsetAsync(g2T, 0, 4096000, stream);

    // GCN branch (bf16 MFMA)
    k_cvt_adj<<<dim3(NNODE, BATCH), blk, 0, stream>>>(adj, adjb);
    k_sup1<<<dim3(125, 16, BATCH), blk, 0, stream>>>(input, gw3, sup1T);
    k_gemm_mfma<128><<<dim3(32, 4, BATCH), blk, 0, stream>>>(adjb, sup1T, g1T);
    k_sup2<<<dim3(125, 8, BATCH), blk, 0, stream>>>(g1T, gb3, gw4, sup2T);
    k_gemm_mfma<64><<<dim3(32, 4, BATCH), blk, 0, stream>>>(adjb, sup2T, g2T);

    // CNN branch + combine (pool reuse safe: stream-ordered after gemm<64>)
    k_prepack<<<dim3(144), blk, 0, stream>>>(cw2, W2p);
    k_conv1<<<dim3(16, 16, BATCH), blk, 0, stream>>>(input, cw1, cb1, h1n);
    k_conv2<<<dim3(8, 32, BATCH), blk, 0, stream>>>(h1n, W2p, cb2, h2);
    k_combine<<<dim3(16, 16, BATCH), blk, 0, stream>>>(
        input, proj, lam, h2, cw3, cb3, g2T, gb4, out);
}

// Round 3
// 669.003 us; speedup vs baseline: 1.0558x; 1.0558x over previous
//
#include <hip/hip_runtime.h>

#define IMG   256
#define NPIX  65536          // 256*256
#define PH    63             // patches per side
#define NNODE 3969           // PH*PH
#define SN    4000           // padded node stride (mult of 32, 16B-aligned rows)
#define HID   64
#define GH    128
#define BATCH 4

typedef __attribute__((ext_vector_type(8))) short short8;
typedef __attribute__((ext_vector_type(4))) float float4v;
typedef unsigned short ushort_t;

__device__ inline ushort_t f2bf(float f) {
    union { float f; unsigned u; } v; v.f = f;
    unsigned r = v.u + 0x7FFF + ((v.u >> 16) & 1);   // RNE
    return (ushort_t)(r >> 16);
}

// ---------------------------------------------------------------------------
// adj fp32 [b][N][N] -> bf16 [b][N][SN], K-pad (3969..3999) zeroed
// ---------------------------------------------------------------------------
__global__ __launch_bounds__(256) void k_cvt_adj(const float* __restrict__ adj,
                                                 ushort_t* __restrict__ adjb) {
    int n = blockIdx.x, b = blockIdx.y;
    const float* src = adj + (size_t)(b * NNODE + n) * NNODE;
    unsigned* dst = (unsigned*)(adjb + (size_t)(b * NNODE + n) * SN);
    for (int c2 = threadIdx.x; c2 < SN / 2; c2 += 256) {
        int c = c2 * 2;
        float f0 = (c < NNODE) ? src[c] : 0.f;
        float f1 = (c + 1 < NNODE) ? src[c + 1] : 0.f;
        dst[c2] = (unsigned)f2bf(f0) | ((unsigned)f2bf(f1) << 16);
    }
}

// ---------------------------------------------------------------------------
// sup1T[b][g][n] = sum_pix patch[n][pix] * w3[pix][g]   (bf16 out, n-pad zeroed)
// ---------------------------------------------------------------------------
__global__ __launch_bounds__(256) void k_sup1(const float* __restrict__ in,
                                              const float* __restrict__ w3,
                                              ushort_t* __restrict__ sup1T) {
    int b = blockIdx.z;
    int g = blockIdx.y * 8 + (threadIdx.x >> 5);
    int n = blockIdx.x * 32 + (threadIdx.x & 31);
    ushort_t* dst = sup1T + (size_t)b * GH * SN + (size_t)g * SN + n;
    if (n >= NNODE) { *dst = 0; return; }
    int py = n / PH, px = n - py * PH;
    const float* base = in + (size_t)b * NPIX + (py * 4) * IMG + px * 4;
    float acc = 0.f;
#pragma unroll
    for (int i = 0; i < 8; ++i)
#pragma unroll
        for (int j = 0; j < 8; ++j)
            acc += base[i * IMG + j] * w3[(i * 8 + j) * GH + g];
    *dst = f2bf(acc);
}

// ---------------------------------------------------------------------------
// MFMA GEMM (transposed form): C[g][n] += sum_k supT[g][k] * adj[n][k]
// BK=64: two K=32 chunks staged+computed per barrier pair.
// ---------------------------------------------------------------------------
template <int G>
__global__ __launch_bounds__(256) void k_gemm_mfma(const ushort_t* __restrict__ adjb,
                                                   const ushort_t* __restrict__ supT,
                                                   float* __restrict__ C) {
    constexpr int FN = (G == 128) ? 4 : 2;
    const int b = blockIdx.z, ks = blockIdx.y;
    const int node0 = blockIdx.x * 128;
    const int t = threadIdx.x;
    const int lane = t & 63, w = t >> 6;
    const int l15 = lane & 15, q = lane >> 4;
    const int wm0 = (G == 128) ? (w & 1) * 64 : 0;
    const int wn0 = (G == 128) ? (w >> 1) * 64 : w * 32;

    __shared__ ushort_t Als[G][72];
    __shared__ ushort_t Bls[128][72];

    const int k0c = ks * 992;
    const int kend = (ks == 3) ? NNODE : k0c + 992;
    const int kiters = (kend - k0c + 31) >> 5;       // 31 (ks<3) or 32 (ks=3)
    const int npairs = (kiters + 1) >> 1;            // 16

    const ushort_t* Ab = supT + (size_t)b * G * SN;
    const ushort_t* Bb = adjb + (size_t)b * NNODE * SN;
    float* Cb = C + (size_t)b * G * SN;

    float4v acc[4][FN];
#pragma unroll
    for (int i = 0; i < 4; ++i)
#pragma unroll
        for (int j = 0; j < FN; ++j)
#pragma unroll
            for (int r = 0; r < 4; ++r) acc[i][j][r] = 0.f;

    for (int kp = 0; kp < npairs; ++kp) {
        const int kb0 = k0c + kp * 64;
        const bool has2 = (kp * 2 + 1 < kiters);     // wave-uniform
#pragma unroll
        for (int i = 0; i < G / 64; ++i) {
            int idx = t + i * 256;
            int r = idx >> 2, s = idx & 3;
            *(uint4*)&Als[r][s * 8] =
                *(const uint4*)&Ab[(size_t)r * SN + kb0 + s * 8];
        }
#pragma unroll
        for (int i = 0; i < 2; ++i) {
            int idx = t + i * 256;
            int r = idx >> 2, s = idx & 3;
            *(uint4*)&Bls[r][s * 8] =
                *(const uint4*)&Bb[(size_t)(node0 + r) * SN + kb0 + s * 8];
        }
        if (has2) {
#pragma unroll
            for (int i = 0; i < G / 64; ++i) {
                int idx = t + i * 256;
                int r = idx >> 2, s = idx & 3;
                *(uint4*)&Als[r][32 + s * 8] =
                    *(const uint4*)&Ab[(size_t)r * SN + kb0 + 32 + s * 8];
            }
#pragma unroll
            for (int i = 0; i < 2; ++i) {
                int idx = t + i * 256;
                int r = idx >> 2, s = idx & 3;
                *(uint4*)&Bls[r][32 + s * 8] =
                    *(const uint4*)&Bb[(size_t)(node0 + r) * SN + kb0 + 32 + s * 8];
            }
        }
        __syncthreads();
        {
            short8 af[4], bf[FN];
#pragma unroll
            for (int i = 0; i < 4; ++i)
                af[i] = *(const short8*)&Als[wm0 + i * 16 + l15][q * 8];
#pragma unroll
            for (int j = 0; j < FN; ++j)
                bf[j] = *(const short8*)&Bls[wn0 + j * 16 + l15][q * 8];
#pragma unroll
            for (int i = 0; i < 4; ++i)
#pragma unroll
                for (int j = 0; j < FN; ++j)
                    acc[i][j] = __builtin_amdgcn_mfma_f32_16x16x32_bf16(
                        af[i], bf[j], acc[i][j], 0, 0, 0);
        }
        if (has2) {
            short8 af[4], bf[FN];
#pragma unroll
            for (int i = 0; i < 4; ++i)
                af[i] = *(const short8*)&Als[wm0 + i * 16 + l15][32 + q * 8];
#pragma unroll
            for (int j = 0; j < FN; ++j)
                bf[j] = *(const short8*)&Bls[wn0 + j * 16 + l15][32 + q * 8];
#pragma unroll
            for (int i = 0; i < 4; ++i)
#pragma unroll
                for (int j = 0; j < FN; ++j)
                    acc[i][j] = __builtin_amdgcn_mfma_f32_16x16x32_bf16(
                        af[i], bf[j], acc[i][j], 0, 0, 0);
        }
        __syncthreads();
    }
#pragma unroll
    for (int i = 0; i < 4; ++i) {
        int gg = wm0 + i * 16 + q * 4;
#pragma unroll
        for (int j = 0; j < FN; ++j) {
            int nn = node0 + wn0 + j * 16 + l15;
            if (nn < NNODE) {
#pragma unroll
                for (int r = 0; r < 4; ++r)
                    unsafeAtomicAdd(&Cb[(size_t)(gg + r) * SN + nn], acc[i][j][r]);
            }
        }
    }
}

// ---------------------------------------------------------------------------
// sup2T[b][g][n] = sum_k relu(g1T[k][n] + gb3[k]) * w4[k][g]  (bf16, pad zeroed)
// ---------------------------------------------------------------------------
__global__ __launch_bounds__(256) void k_sup2(const float* __restrict__ g1T,
                                              const float* __restrict__ gb3,
                                              const float* __restrict__ w4,
                                              ushort_t* __restrict__ sup2T) {
    int b = blockIdx.z;
    int g = blockIdx.y * 8 + (threadIdx.x >> 5);
    int n = blockIdx.x * 32 + (threadIdx.x & 31);
    const float* gb = g1T + (size_t)b * GH * SN + n;
    float acc = 0.f;
#pragma unroll 8
    for (int k = 0; k < GH; ++k) {
        float v = fmaxf(gb[(size_t)k * SN] + gb3[k], 0.f);
        acc += v * w4[k * 64 + g];
    }
    sup2T[(size_t)b * 64 * SN + (size_t)g * SN + n] = (n < NNODE) ? f2bf(acc) : 0;
}

// ---------------------------------------------------------------------------
// prepack conv2 weights: cw2 [oc][ic][3][3] fp32 -> W2p [tap][oc][ic] bf16
// ---------------------------------------------------------------------------
__global__ __launch_bounds__(256) void k_prepack(const float* __restrict__ w,
                                                 ushort_t* __restrict__ W2p) {
    int idx = blockIdx.x * 256 + threadIdx.x;   // 9*64*64 = 36864
    if (idx >= 36864) return;
    int tap = idx >> 12, rem = idx & 4095;
    int oc = rem >> 6, ic = rem & 63;
    W2p[idx] = f2bf(w[(oc * 64 + ic) * 9 + tap]);
}

// ---------------------------------------------------------------------------
// conv2f: FUSED conv1 -> conv2(MFMA) -> conv3 channel-contraction.
//   - conv1 (1->64ch, relu, bf16) recomputed in-block for the 34x10 halo from
//     a 36x12 raw-input tile (identical op order + f2bf => bitwise == old h1n)
//   - conv2 implicit-GEMM MFMA identical to before (64oc x 32x8 px, K=9x64)
//   - epilogue: h = relu(acc+b2); u_d(p) = sum_oc h*w3c[oc][d] via in-register
//     partials + q-group shfl_xor butterfly (lanes sharing l15 hold the same
//     pixel, different oc)  -> writes 9 planes U[d][pix] fp32 (9.4 MB total)
//     instead of 64-plane h2 (67 MB).
// LDS: Xs 48,960 + pre 4,352 = 53,312 B  -> 3 blocks/CU (unchanged occupancy).
// pre[] overlay: phase A = sI[432] | ws1[576] | bs1[64]; phase B = w3c[576].
// ---------------------------------------------------------------------------
__global__ __launch_bounds__(256) void k_conv2f(const float* __restrict__ in,
                                                const float* __restrict__ w1,
                                                const float* __restrict__ b1,
                                                const ushort_t* __restrict__ W2p,
                                                const float* __restrict__ b2,
                                                const float* __restrict__ w3c,
                                                float* __restrict__ U) {
    __shared__ ushort_t Xs[340 * 72];           // 48,960 B
    __shared__ float pre[1088];                 // 4,352 B (overlaid)
    const int b = blockIdx.z;
    const float* inb = in + (size_t)b * NPIX;
    float* Uball = U + (size_t)b * 9 * NPIX;
    const int t = threadIdx.x;
    const int lane = t & 63, w = t >> 6;
    const int l15 = lane & 15, q = lane >> 4;
    const int x0 = blockIdx.x * 32, y0 = blockIdx.y * 8;

    float* sI  = pre;                           // [12][36] input halo^2
    float* ws1 = pre + 432;                     // [576] conv1 weights
    float* bs1 = pre + 1008;                    // [64]  conv1 bias

    for (int idx = t; idx < 432; idx += 256) {
        int yy = idx / 36, xx = idx - yy * 36;
        int gy = y0 + yy - 2, gx = x0 + xx - 2;
        sI[idx] = (gy >= 0 && gy < IMG && gx >= 0 && gx < IMG) ? inb[gy * IMG + gx] : 0.f;
    }
    for (int idx = t; idx < 576; idx += 256) ws1[idx] = w1[idx];
    if (t < 64) bs1[t] = b1[t];
    __syncthreads();

    // conv1 -> Xs: 340 halo px x 64 ch (8 ch per (px,s) work item)
    for (int idx = t; idx < 2720; idx += 256) {
        int hp = idx >> 3, s = idx & 7;
        int hy = hp / 34, hx = hp - hy * 34;
        int gy = y0 + hy - 1, gx = x0 + hx - 1;
        unsigned pk[4] = {0u, 0u, 0u, 0u};
        if (gy >= 0 && gy < IMG && gx >= 0 && gx < IMG) {
            float r[9];
#pragma unroll
            for (int dy = 0; dy < 3; ++dy)
#pragma unroll
                for (int dx = 0; dx < 3; ++dx)
                    r[dy * 3 + dx] = sI[(hy + dy) * 36 + hx + dx];
#pragma unroll
            for (int h = 0; h < 4; ++h) {
                int oc0 = s * 8 + h * 2;
                float a0 = bs1[oc0], a1 = bs1[oc0 + 1];
#pragma unroll
                for (int k = 0; k < 9; ++k) {
                    a0 += r[k] * ws1[oc0 * 9 + k];
                    a1 += r[k] * ws1[(oc0 + 1) * 9 + k];
                }
                a0 = fmaxf(a0, 0.f); a1 = fmaxf(a1, 0.f);
                pk[h] = (unsigned)f2bf(a0) | ((unsigned)f2bf(a1) << 16);
            }
        }
        *(uint4*)&Xs[hp * 72 + s * 8] = *(uint4*)pk;
    }
    __syncthreads();                             // Xs ready; pre phase-A reads done

    // phase B: stage conv3 weights into pre (K-loop reads only Xs/W2p)
    for (int idx = t; idx < 576; idx += 256) pre[idx] = w3c[idx];

    const int wn0 = w * 64;
    int pbase[4];
#pragma unroll
    for (int j = 0; j < 4; ++j) {
        int p = wn0 + j * 16 + l15;
        pbase[j] = (p >> 5) * 34 + (p & 31);
    }

    float4v acc[4][4];
#pragma unroll
    for (int i = 0; i < 4; ++i)
#pragma unroll
        for (int j = 0; j < 4; ++j)
#pragma unroll
            for (int r = 0; r < 4; ++r) acc[i][j][r] = 0.f;

    for (int tap = 0; tap < 9; ++tap) {
        int ky = tap / 3, kx = tap - ky * 3;
        const ushort_t* wp = W2p + tap * 4096;
#pragma unroll
        for (int c = 0; c < 2; ++c) {
            short8 af[4], bf[4];
#pragma unroll
            for (int i = 0; i < 4; ++i)
                af[i] = *(const short8*)&wp[(i * 16 + l15) * 64 + c * 32 + q * 8];
#pragma unroll
            for (int j = 0; j < 4; ++j)
                bf[j] = *(const short8*)&Xs[(pbase[j] + ky * 34 + kx) * 72 + c * 32 + q * 8];
#pragma unroll
            for (int i = 0; i < 4; ++i)
#pragma unroll
                for (int j = 0; j < 4; ++j)
                    acc[i][j] = __builtin_amdgcn_mfma_f32_16x16x32_bf16(
                        af[i], bf[j], acc[i][j], 0, 0, 0);
        }
    }
    __syncthreads();                             // w3c visible to all threads

    // epilogue: relu(conv2+b2), contract over oc against w3c -> 9 U planes
    float b2r[16];
#pragma unroll
    for (int i = 0; i < 4; ++i)
#pragma unroll
        for (int r = 0; r < 4; ++r) b2r[i * 4 + r] = b2[i * 16 + q * 4 + r];

#pragma unroll
    for (int j = 0; j < 4; ++j) {
        float u[9];
#pragma unroll
        for (int d = 0; d < 9; ++d) u[d] = 0.f;
#pragma unroll
        for (int i = 0; i < 4; ++i)
#pragma unroll
            for (int r = 0; r < 4; ++r) {
                int oc = i * 16 + q * 4 + r;
                float h = fmaxf(acc[i][j][r] + b2r[i * 4 + r], 0.f);
#pragma unroll
                for (int d = 0; d < 9; ++d) u[d] += h * pre[oc * 9 + d];
            }
#pragma unroll
        for (int d = 0; d < 9; ++d) {
            u[d] += __shfl_xor(u[d], 16, 64);
            u[d] += __shfl_xor(u[d], 32, 64);
        }
        int p = wn0 + j * 16 + l15;
        int y = y0 + (p >> 5), x = x0 + (p & 31);
#pragma unroll
        for (int dd = 0; dd < 3; ++dd) {
            int d = q + dd * 4;                 // q0:{0,4,8} q1:{1,5} q2:{2,6} q3:{3,7}
            if (d < 9)
                Uball[(size_t)d * NPIX + (size_t)y * IMG + x] = u[d];
        }
    }
}

// ---------------------------------------------------------------------------
// combine: out = relu( tmp1 + [bc3 + sum_d U_d(p+off(d))] + gather(g2T+gb4)/cnt )
// no LDS, no barriers.
// ---------------------------------------------------------------------------
__global__ __launch_bounds__(256) void k_combine(const float* __restrict__ in,
                                                 const float* __restrict__ proj,
                                                 const float* __restrict__ lamp,
                                                 const float* __restrict__ U,
                                                 const float* __restrict__ bc,
                                                 const float* __restrict__ g2T,
                                                 const float* __restrict__ gb4,
                                                 float* __restrict__ out) {
    int b = blockIdx.z;
    const float* inb = in + (size_t)b * NPIX;
    const float* prb = proj + (size_t)b * NPIX;
    const float* Ub = U + (size_t)b * 9 * NPIX;
    const float* g2b = g2T + (size_t)b * 64 * SN;
    int tx = threadIdx.x & 15, ty = threadIdx.x >> 4;
    int x = blockIdx.x * 16 + tx, y = blockIdx.y * 16 + ty;

    float acc = bc[0];
#pragma unroll
    for (int dy = 0; dy < 3; ++dy) {
        int yy = y + dy - 1;
#pragma unroll
        for (int dx = 0; dx < 3; ++dx) {
            int xx = x + dx - 1;
            if (yy >= 0 && yy < IMG && xx >= 0 && xx < IMG)
                acc += Ub[(size_t)(dy * 3 + dx) * NPIX + (size_t)yy * IMG + xx];
        }
    }

    float iv = inb[y * IMG + x], pv = prb[y * IMG + x];
    float tmp1 = iv + lamp[0] * (pv - iv);

    int pylo = (y >= 4) ? ((y - 4) >> 2) : 0;
    int pyhi = min(62, y >> 2);
    int pxlo = (x >= 4) ? ((x - 4) >> 2) : 0;
    int pxhi = min(62, x >> 2);
    float sum = 0.f;
    int cnt = 0;
    for (int py = pylo; py <= pyhi; ++py)
        for (int px = pxlo; px <= pxhi; ++px) {
            int pix = (y - 4 * py) * 8 + (x - 4 * px);
            sum += g2b[(size_t)pix * SN + (py * PH + px)] + gb4[pix];
            ++cnt;
        }
    float tmp3 = sum / (float)cnt;

    out[(size_t)b * NPIX + y * IMG + x] = fmaxf(tmp1 + acc + tmp3, 0.f);
}

// ---------------------------------------------------------------------------
extern "C" void kernel_launch(void* const* d_in, const int* in_sizes, int n_in,
                              void* d_out, int out_size, void* d_ws, size_t ws_size,
                              hipStream_t stream) {
    const float* input = (const float*)d_in[0];
    const float* proj  = (const float*)d_in[1];
    const float* adj   = (const float*)d_in[2];
    const float* lam   = (const float*)d_in[3];
    const float* cw1   = (const float*)d_in[4];
    const float* cb1   = (const float*)d_in[5];
    const float* cw2   = (const float*)d_in[6];
    const float* cb2   = (const float*)d_in[7];
    const float* cw3   = (const float*)d_in[8];
    const float* cb3   = (const float*)d_in[9];
    const float* gw3   = (const float*)d_in[10];
    const float* gb3   = (const float*)d_in[11];
    const float* gw4   = (const float*)d_in[12];
    const float* gb4   = (const float*)d_in[13];
    float* out = (float*)d_out;

    // ws layout (bytes):
    //   g2T fp32 [4][64][SN]                    @ 0          (4,096,000)
    //   pool @ 4,096,000:
    //     GCN phase: adjb bf16 [4][N][SN]       (127,008,000)
    //                sup1T bf16 [4][128][SN]    (4,096,000)
    //                g1T  fp32 [4][128][SN]     (8,192,000)
    //                sup2T bf16 [4][64][SN]     (2,048,000)
    //     conv phase (reuses pool, stream-ordered after gemm<64>):
    //                U   fp32 [4][9][NPIX]      (9,437,184)
    //                W2p bf16 [9][64][64]       (73,728)
    char* base = (char*)d_ws;
    float*    g2T   = (float*)base;
    char*     pool  = base + 4096000;
    ushort_t* adjb  = (ushort_t*)pool;
    ushort_t* sup1T = (ushort_t*)(pool + 127008000);
    float*    g1T   = (float*)(pool + 127008000 + 4096000);
    ushort_t* sup2T = (ushort_t*)(pool + 127008000 + 4096000 + 8192000);
    float*    U     = (float*)pool;
    ushort_t* W2p   = (ushort_t*)(pool + 9437184);

    dim3 blk(256);

    hipMemsetAsync(g1T, 0, 8192000, stream);
    hipMemsetAsync(g2T, 0, 4096000, stream);

    // GCN branch (bf16 MFMA)
    k_cvt_adj<<<dim3(NNODE, BATCH), blk, 0, stream>>>(adj, adjb);
    k_sup1<<<dim3(125, 16, BATCH), blk, 0, stream>>>(input, gw3, sup1T);
    k_gemm_mfma<128><<<dim3(32, 4, BATCH), blk, 0, stream>>>(adjb, sup1T, g1T);
    k_sup2<<<dim3(125, 8, BATCH), blk, 0, stream>>>(g1T, gb3, gw4, sup2T);
    k_gemm_mfma<64><<<dim3(32, 4, BATCH), blk, 0, stream>>>(adjb, sup2T, g2T);

    // CNN branch + combine (pool reuse safe: stream-ordered after gemm<64>)
    k_prepack<<<dim3(144), blk, 0, stream>>>(cw2, W2p);
    k_conv2f<<<dim3(8, 32, BATCH), blk, 0, stream>>>(input, cw1, cb1, W2p, cb2, cw3, U);
    k_combine<<<dim3(16, 16, BATCH), blk, 0, stream>>>(
        input, proj, lam, U, cb3, g2T, gb4, out);
}